// Round 2
// baseline (369.865 us; speedup 1.0000x reference)
//
#include <hip/hip_runtime.h>

#define BB 16
#define NN 38400
#define DD 64
#define SS 7
#define TILE 128

__device__ __forceinline__ float wsum64(float v) {
#pragma unroll
  for (int off = 32; off > 0; off >>= 1) v += __shfl_xor(v, off);
  return v;
}

// ---------------------------------------------------------------------------
// Slot-side kernel: 112 blocks (one per (b,s)), 64 threads (lane = d).
// mode 0: init slots from mu/log_sigma/slots_init, then tail
// mode 1: GRU + MLP update from accumulators, then tail
// mode 2: GRU + MLP update, write final slots to d_out, no tail
// tail: LN_slot -> q -> qk (scale folded) -> gqk = g_in*qk, sgq, cb;
//       zero ACC/ACCM/Z for the upcoming main kernel.
// ---------------------------------------------------------------------------
__global__ __launch_bounds__(64) void k_slot(
    int mode,
    const float* __restrict__ slots_init, const float* __restrict__ mu,
    const float* __restrict__ lsig,
    const float* __restrict__ ln_slot_g, const float* __restrict__ ln_slot_b,
    const float* __restrict__ ln_mlp_g, const float* __restrict__ ln_mlp_b,
    const float* __restrict__ ln_in_g, const float* __restrict__ ln_in_b,
    const float* __restrict__ Wq, const float* __restrict__ Wk,
    const float* __restrict__ Wv,
    const float* __restrict__ W_ih, const float* __restrict__ W_hh,
    const float* __restrict__ b_ih, const float* __restrict__ b_hh,
    const float* __restrict__ W1, const float* __restrict__ b1,
    const float* __restrict__ W2, const float* __restrict__ b2,
    float* __restrict__ slots, float* __restrict__ gqk,
    float* __restrict__ sc,
    float* __restrict__ ACC, float* __restrict__ ACCM, float* __restrict__ Zg,
    float* __restrict__ out)
{
  const int bs = blockIdx.x;
  const int b = bs / SS, s = bs % SS;
  const int d = threadIdx.x;
  __shared__ float t0[64], t1[64], hh[128];

  float slot;
  if (mode == 0) {
    slot = mu[d] + __expf(lsig[d]) * slots_init[bs * 64 + d];
  } else {
    // updates = ((g_in*(ACC-ACCM) + b_in*Z)/Z) @ Wv^T
    const float zv = Zg[b * 8 + s];
    const float am = ACCM[b * 8 + s];
    const float ac = ACC[(b * 8 + s) * 64 + d];
    const float ubar = (ln_in_g[d] * (ac - am) + ln_in_b[d] * zv) / zv;
    t0[d] = ubar;
    __syncthreads();
    float upd = 0.f;
#pragma unroll
    for (int e = 0; e < 64; ++e) upd += t0[e] * Wv[d * 64 + e];
    const float sp = slots[bs * 64 + d];
    __syncthreads();
    t0[d] = upd;
    t1[d] = sp;
    __syncthreads();
    // GRU gates (torch order r,z,n)
    float s_r = b_ih[d] + b_hh[d];
    float s_z = b_ih[64 + d] + b_hh[64 + d];
    float i_n = b_ih[128 + d];
    float h_n = b_hh[128 + d];
#pragma unroll
    for (int e = 0; e < 64; ++e) {
      const float u = t0[e], p = t1[e];
      s_r += u * W_ih[d * 64 + e] + p * W_hh[d * 64 + e];
      s_z += u * W_ih[(64 + d) * 64 + e] + p * W_hh[(64 + d) * 64 + e];
      i_n += u * W_ih[(128 + d) * 64 + e];
      h_n += p * W_hh[(128 + d) * 64 + e];
    }
    const float rg = 1.f / (1.f + __expf(-s_r));
    const float zg = 1.f / (1.f + __expf(-s_z));
    const float ng = tanhf(i_n + rg * h_n);
    const float hv = (1.f - zg) * ng + zg * sp;
    // residual MLP
    const float mn = wsum64(hv) * (1.f / 64.f);
    const float dv = hv - mn;
    const float vr = wsum64(dv * dv) * (1.f / 64.f);
    const float rs = rsqrtf(vr + 1e-5f);
    const float mld = dv * rs * ln_mlp_g[d] + ln_mlp_b[d];
    __syncthreads();
    t0[d] = mld;
    __syncthreads();
    float h0 = b1[d], h1 = b1[64 + d];
#pragma unroll
    for (int e = 0; e < 64; ++e) {
      const float m = t0[e];
      h0 += m * W1[d * 64 + e];
      h1 += m * W1[(64 + d) * 64 + e];
    }
    hh[d] = fmaxf(h0, 0.f);
    hh[64 + d] = fmaxf(h1, 0.f);
    __syncthreads();
    float o = hv + b2[d];
#pragma unroll
    for (int j = 0; j < 128; ++j) o += hh[j] * W2[d * 128 + j];
    slot = o;
  }

  if (mode == 2) {
    out[bs * 64 + d] = slot;
    return;
  }
  slots[bs * 64 + d] = slot;

  // tail: compute gqk / sgq / cb for next main pass
  const float mn = wsum64(slot) * (1.f / 64.f);
  const float dv = slot - mn;
  const float vr = wsum64(dv * dv) * (1.f / 64.f);
  const float rs = rsqrtf(vr + 1e-5f);
  const float sln = dv * rs * ln_slot_g[d] + ln_slot_b[d];
  __syncthreads();
  t0[d] = sln;
  __syncthreads();
  float qv = 0.f;
#pragma unroll
  for (int e = 0; e < 64; ++e) qv += t0[e] * Wq[d * 64 + e];
  __syncthreads();
  t1[d] = qv;
  __syncthreads();
  float qe = 0.f;  // lane d plays role of e here
#pragma unroll
  for (int dd = 0; dd < 64; ++dd) qe += t1[dd] * Wk[dd * 64 + d];
  qe *= 0.125f;  // scale = D^-0.5
  const float gq = ln_in_g[d] * qe;
  gqk[(b * 8 + s) * 64 + d] = gq;
  const float sg = wsum64(gq);
  const float cb = wsum64(ln_in_b[d] * qe);
  if (d == 0) {
    sc[(b * 8 + s) * 2 + 0] = sg;
    sc[(b * 8 + s) * 2 + 1] = cb;
  }
  // zero accumulators for upcoming main kernel
  ACC[(b * 8 + s) * 64 + d] = 0.f;
  if (d == 0) {
    ACCM[b * 8 + s] = 0.f;
    Zg[b * 8 + s] = 0.f;
  }
}

// ---------------------------------------------------------------------------
// Main kernel: grid (300, 16), 512 threads. One 128-row tile per block.
// Stage : coalesced float4 global loads -> LDS with 16B-granule XOR swizzle
//         (pos = chunk ^ (row & 15)) — keeps b128 alignment, even bank use
//         on staging writes, row reads (phase 1) and column reads (phase 2).
// Phase1: 4 lanes per row (16 floats each): dots vs gqk + LN stats,
//         2-step shfl_xor quad reduce, softmax replicated; store p*rstd
//         into pa[7][128]; wave-reduce Z and ACCM partials (offsets 4..32
//         visit one lane per row).
// Phase2: wave w computes slot w (w<7): column-read xs from LDS (swizzled,
//         2-way max = free), broadcast float4 reads of pa; one atomicAdd
//         per (s,d).
// ---------------------------------------------------------------------------
__global__ __launch_bounds__(512, 8) void k_main(
    const float* __restrict__ x,
    const float* __restrict__ gqk,  // [B][8][64] (g_in ⊙ scale·Wk^T q)
    const float* __restrict__ sc,   // [B][8][2]  (sgq, cb)
    float* __restrict__ ACC, float* __restrict__ ACCM, float* __restrict__ Zg)
{
  __shared__ __align__(16) float xs[TILE * 64];
  __shared__ __align__(16) float pa[7 * TILE];
  __shared__ float wz[8][8], wm[8][8];
  const int t = threadIdx.x;
  const int b = blockIdx.y;
  const int row0 = blockIdx.x * TILE;

  // ---- stage: 32KB tile, coalesced, XOR-swizzled LDS ----
  const float4* src =
      reinterpret_cast<const float4*>(x + ((size_t)b * NN + row0) * 64);
#pragma unroll
  for (int i = 0; i < 4; ++i) {
    const int f = i * 512 + t;  // flat 16B-chunk index, 0..2047
    const float4 v = src[f];
    const int r = f >> 4, c = f & 15;
    *reinterpret_cast<float4*>(&xs[(r << 6) + ((c ^ (r & 15)) << 2)]) = v;
  }
  const float* qb = gqk + b * 512;
  const float* scb = sc + b * 16;
  __syncthreads();

  // ---- phase 1: logits + LN stats + softmax ----
  const int row = t >> 2, q = t & 3;
  float lg[7] = {0.f, 0.f, 0.f, 0.f, 0.f, 0.f, 0.f};
  float sum = 0.f, sq = 0.f;
#pragma unroll
  for (int j = 0; j < 4; ++j) {
    const int c = q * 4 + j;
    const float4 v = *reinterpret_cast<const float4*>(
        &xs[(row << 6) + ((c ^ (row & 15)) << 2)]);
    sum += v.x + v.y + v.z + v.w;
    sq += v.x * v.x + v.y * v.y + v.z * v.z + v.w * v.w;
#pragma unroll
    for (int s2 = 0; s2 < 7; ++s2) {
      const float4 g4 = *reinterpret_cast<const float4*>(&qb[s2 * 64 + c * 4]);
      lg[s2] += v.x * g4.x + v.y * g4.y + v.z * g4.z + v.w * g4.w;
    }
  }
#pragma unroll
  for (int off = 1; off <= 2; off <<= 1) {
    sum += __shfl_xor(sum, off);
    sq += __shfl_xor(sq, off);
#pragma unroll
    for (int s2 = 0; s2 < 7; ++s2) lg[s2] += __shfl_xor(lg[s2], off);
  }
  const float mean = sum * (1.f / 64.f);
  const float var = sq * (1.f / 64.f) - mean * mean;
  const float rstd = rsqrtf(var + 1e-5f);
  const float rm = rstd * mean;

  float mx = -1e30f;
#pragma unroll
  for (int s2 = 0; s2 < 7; ++s2) {
    lg[s2] = rstd * lg[s2] - rm * scb[s2 * 2] + scb[s2 * 2 + 1];
    mx = fmaxf(mx, lg[s2]);
  }
  float se = 0.f;
#pragma unroll
  for (int s2 = 0; s2 < 7; ++s2) {
    lg[s2] = __expf(lg[s2] - mx);
    se += lg[s2];
  }
  const float inv = 1.f / se;
#pragma unroll
  for (int s2 = 0; s2 < 7; ++s2) lg[s2] = lg[s2] * inv + 1e-8f;  // p

  if (q == 0) {
#pragma unroll
    for (int s2 = 0; s2 < 7; ++s2) pa[s2 * TILE + row] = lg[s2] * rstd;
  }
  // per-wave Z / ACCM partials (lanes hold p duplicated x4; offsets 4..32
  // touch exactly one lane per row)
#pragma unroll
  for (int s2 = 0; s2 < 7; ++s2) {
    float z = lg[s2];
    float a = lg[s2] * rm;
#pragma unroll
    for (int off = 4; off <= 32; off <<= 1) {
      z += __shfl_xor(z, off);
      a += __shfl_xor(a, off);
    }
    if ((t & 63) == 0) {
      wz[t >> 6][s2] = z;
      wm[t >> 6][s2] = a;
    }
  }
  __syncthreads();
  if (t < 7) {
    float z = 0.f, a = 0.f;
#pragma unroll
    for (int w = 0; w < 8; ++w) {
      z += wz[w][t];
      a += wm[w][t];
    }
    atomicAdd(&Zg[b * 8 + t], z);
    atomicAdd(&ACCM[b * 8 + t], a);
  }

  // ---- phase 2: ACC[s][d] += sum_n (p*rstd)[n] * x[n][d], all from LDS ----
  const int s = t >> 6;
  if (s < 7) {
    const int d = t & 63;
    const int ch = d >> 2, sub = d & 3;
    const float* pas = pa + s * TILE;
    float acc = 0.f;
#pragma unroll 4
    for (int n4 = 0; n4 < TILE / 4; ++n4) {
      const float4 p4 = *reinterpret_cast<const float4*>(&pas[n4 * 4]);
      const int n = n4 * 4;
      acc += p4.x * xs[((n + 0) << 6) + ((ch ^ ((n + 0) & 15)) << 2) + sub];
      acc += p4.y * xs[((n + 1) << 6) + ((ch ^ ((n + 1) & 15)) << 2) + sub];
      acc += p4.z * xs[((n + 2) << 6) + ((ch ^ ((n + 2) & 15)) << 2) + sub];
      acc += p4.w * xs[((n + 3) << 6) + ((ch ^ ((n + 3) & 15)) << 2) + sub];
    }
    atomicAdd(&ACC[(b * 8 + s) * 64 + d], acc);
  }
}

extern "C" void kernel_launch(void* const* d_in, const int* in_sizes, int n_in,
                              void* d_out, int out_size, void* d_ws,
                              size_t ws_size, hipStream_t stream) {
  const float* inputs     = (const float*)d_in[0];
  const float* slots_init = (const float*)d_in[1];
  const float* slots_mu   = (const float*)d_in[2];
  const float* slots_lsig = (const float*)d_in[3];
  const float* ln_in_g    = (const float*)d_in[4];
  const float* ln_in_b    = (const float*)d_in[5];
  const float* ln_slot_g  = (const float*)d_in[6];
  const float* ln_slot_b  = (const float*)d_in[7];
  const float* ln_mlp_g   = (const float*)d_in[8];
  const float* ln_mlp_b   = (const float*)d_in[9];
  const float* Wq   = (const float*)d_in[10];
  const float* Wk   = (const float*)d_in[11];
  const float* Wv   = (const float*)d_in[12];
  const float* W_ih = (const float*)d_in[13];
  const float* W_hh = (const float*)d_in[14];
  const float* b_ih = (const float*)d_in[15];
  const float* b_hh = (const float*)d_in[16];
  const float* W1   = (const float*)d_in[17];
  const float* b1   = (const float*)d_in[18];
  const float* W2   = (const float*)d_in[19];
  const float* b2   = (const float*)d_in[20];

  float* ws    = (float*)d_ws;
  float* slots = ws;            // B*S*64 = 7168
  float* gqk   = ws + 7168;     // B*8*64 = 8192
  float* sc    = gqk + 8192;    // B*8*2  = 256
  float* ACC   = sc + 256;      // B*8*64 = 8192
  float* ACCM  = ACC + 8192;    // B*8    = 128
  float* Zg    = ACCM + 128;    // B*8    = 128

  float* out = (float*)d_out;

#define SLOT_ARGS                                                          \
  slots_init, slots_mu, slots_lsig, ln_slot_g, ln_slot_b, ln_mlp_g,        \
      ln_mlp_b, ln_in_g, ln_in_b, Wq, Wk, Wv, W_ih, W_hh, b_ih, b_hh, W1,  \
      b1, W2, b2, slots, gqk, sc, ACC, ACCM, Zg, out

  k_slot<<<112, 64, 0, stream>>>(0, SLOT_ARGS);
  for (int it = 0; it < 3; ++it) {
    k_main<<<dim3(NN / TILE, BB), 512, 0, stream>>>(inputs, gqk, sc, ACC,
                                                    ACCM, Zg);
    k_slot<<<112, 64, 0, stream>>>(it == 2 ? 2 : 1, SLOT_ARGS);
  }
#undef SLOT_ARGS
}

// Round 3
// 314.331 us; speedup vs baseline: 1.1767x; 1.1767x over previous
//
#include <hip/hip_runtime.h>

#define BB 16
#define NN 38400
#define DD 64
#define SS 7

// k_main geometry: 64-row tiles, 5 tiles per wave, 4 waves per block.
#define TROWS 64
#define TPW 5
#define ROWS_PER_WAVE (TROWS * TPW)            // 320
#define WPB_BATCH (NN / ROWS_PER_WAVE)         // 120 waves per batch
#define NBLOCKS (BB * WPB_BATCH / 4)           // 480
#define XST 68                                 // LDS row stride (floats)

__device__ __forceinline__ float wsum64(float v) {
#pragma unroll
  for (int off = 32; off > 0; off >>= 1) v += __shfl_xor(v, off);
  return v;
}

// ---------------------------------------------------------------------------
// Slot-side kernel (unchanged from the passing version): 112 blocks, 64 thr.
// mode 0: init slots; mode 1: GRU+MLP update; mode 2: update + write out.
// tail (modes 0,1): LN_slot -> q -> gqk/sgq/cb; zero ACC/ACCM/Z.
// ---------------------------------------------------------------------------
__global__ __launch_bounds__(64) void k_slot(
    int mode,
    const float* __restrict__ slots_init, const float* __restrict__ mu,
    const float* __restrict__ lsig,
    const float* __restrict__ ln_slot_g, const float* __restrict__ ln_slot_b,
    const float* __restrict__ ln_mlp_g, const float* __restrict__ ln_mlp_b,
    const float* __restrict__ ln_in_g, const float* __restrict__ ln_in_b,
    const float* __restrict__ Wq, const float* __restrict__ Wk,
    const float* __restrict__ Wv,
    const float* __restrict__ W_ih, const float* __restrict__ W_hh,
    const float* __restrict__ b_ih, const float* __restrict__ b_hh,
    const float* __restrict__ W1, const float* __restrict__ b1,
    const float* __restrict__ W2, const float* __restrict__ b2,
    float* __restrict__ slots, float* __restrict__ gqk,
    float* __restrict__ sc,
    float* __restrict__ ACC, float* __restrict__ ACCM, float* __restrict__ Zg,
    float* __restrict__ out)
{
  const int bs = blockIdx.x;
  const int b = bs / SS, s = bs % SS;
  const int d = threadIdx.x;
  __shared__ float t0[64], t1[64], hh[128];

  float slot;
  if (mode == 0) {
    slot = mu[d] + __expf(lsig[d]) * slots_init[bs * 64 + d];
  } else {
    const float zv = Zg[b * 8 + s];
    const float am = ACCM[b * 8 + s];
    const float ac = ACC[(b * 8 + s) * 64 + d];
    const float ubar = (ln_in_g[d] * (ac - am) + ln_in_b[d] * zv) / zv;
    t0[d] = ubar;
    __syncthreads();
    float upd = 0.f;
#pragma unroll
    for (int e = 0; e < 64; ++e) upd += t0[e] * Wv[d * 64 + e];
    const float sp = slots[bs * 64 + d];
    __syncthreads();
    t0[d] = upd;
    t1[d] = sp;
    __syncthreads();
    float s_r = b_ih[d] + b_hh[d];
    float s_z = b_ih[64 + d] + b_hh[64 + d];
    float i_n = b_ih[128 + d];
    float h_n = b_hh[128 + d];
#pragma unroll
    for (int e = 0; e < 64; ++e) {
      const float u = t0[e], p = t1[e];
      s_r += u * W_ih[d * 64 + e] + p * W_hh[d * 64 + e];
      s_z += u * W_ih[(64 + d) * 64 + e] + p * W_hh[(64 + d) * 64 + e];
      i_n += u * W_ih[(128 + d) * 64 + e];
      h_n += p * W_hh[(128 + d) * 64 + e];
    }
    const float rg = 1.f / (1.f + __expf(-s_r));
    const float zg = 1.f / (1.f + __expf(-s_z));
    const float ng = tanhf(i_n + rg * h_n);
    const float hv = (1.f - zg) * ng + zg * sp;
    const float mn = wsum64(hv) * (1.f / 64.f);
    const float dv = hv - mn;
    const float vr = wsum64(dv * dv) * (1.f / 64.f);
    const float rs = rsqrtf(vr + 1e-5f);
    const float mld = dv * rs * ln_mlp_g[d] + ln_mlp_b[d];
    __syncthreads();
    t0[d] = mld;
    __syncthreads();
    float h0 = b1[d], h1 = b1[64 + d];
#pragma unroll
    for (int e = 0; e < 64; ++e) {
      const float m = t0[e];
      h0 += m * W1[d * 64 + e];
      h1 += m * W1[(64 + d) * 64 + e];
    }
    hh[d] = fmaxf(h0, 0.f);
    hh[64 + d] = fmaxf(h1, 0.f);
    __syncthreads();
    float o = hv + b2[d];
#pragma unroll
    for (int j = 0; j < 128; ++j) o += hh[j] * W2[d * 128 + j];
    slot = o;
  }

  if (mode == 2) {
    out[bs * 64 + d] = slot;
    return;
  }
  slots[bs * 64 + d] = slot;

  const float mn = wsum64(slot) * (1.f / 64.f);
  const float dv = slot - mn;
  const float vr = wsum64(dv * dv) * (1.f / 64.f);
  const float rs = rsqrtf(vr + 1e-5f);
  const float sln = dv * rs * ln_slot_g[d] + ln_slot_b[d];
  __syncthreads();
  t0[d] = sln;
  __syncthreads();
  float qv = 0.f;
#pragma unroll
  for (int e = 0; e < 64; ++e) qv += t0[e] * Wq[d * 64 + e];
  __syncthreads();
  t1[d] = qv;
  __syncthreads();
  float qe = 0.f;
#pragma unroll
  for (int dd = 0; dd < 64; ++dd) qe += t1[dd] * Wk[dd * 64 + d];
  qe *= 0.125f;  // scale = D^-0.5
  const float gq = ln_in_g[d] * qe;
  gqk[(b * 8 + s) * 64 + d] = gq;
  const float sg = wsum64(gq);
  const float cb = wsum64(ln_in_b[d] * qe);
  if (d == 0) {
    sc[(b * 8 + s) * 2 + 0] = sg;
    sc[(b * 8 + s) * 2 + 1] = cb;
  }
  ACC[(b * 8 + s) * 64 + d] = 0.f;
  if (d == 0) {
    ACCM[b * 8 + s] = 0.f;
    Zg[b * 8 + s] = 0.f;
  }
}

// ---------------------------------------------------------------------------
// Main kernel: 480 blocks x 256 threads. Each WAVE independently streams 5
// 64-row tiles (batch-uniform) with a register-prefetch pipeline:
//   load tile i+1 -> regs  |  phase1+phase2 tile i from LDS  |  ds_write i+1
// LDS row stride 68 floats => staging writes, row b128 reads, and column
// reads are all bank-even with zero swizzle arithmetic. Accumulators (ACC
// partials, Z, ACCM) live in registers across all 5 tiles; one flush/wave.
// ---------------------------------------------------------------------------
__global__ __launch_bounds__(256, 2) void k_main(
    const float* __restrict__ x,
    const float* __restrict__ gqk,  // [B][8][64] (g_in ⊙ scale·Wk^T q)
    const float* __restrict__ sc,   // [B][8][2]  (sgq, cb)
    float* __restrict__ ACC, float* __restrict__ ACCM, float* __restrict__ Zg)
{
  __shared__ __align__(16) float xs_all[4][TROWS * XST];  // 69632 B
  __shared__ __align__(16) float pa_all[4][TROWS * 8];    // 8192 B
  __shared__ __align__(16) float qbs[512];                // 2048 B
  __shared__ float scs[16];

  const int t = threadIdx.x;
  const int lane = t & 63;
  const int w = t >> 6;
  const int W = blockIdx.x * 4 + w;
  const int b = W / WPB_BATCH;
  const int rw0 = (W % WPB_BATCH) * ROWS_PER_WAVE;

  // stage gqk/sc for this batch (block-uniform: all 4 waves same b)
  qbs[t] = gqk[b * 512 + t];
  qbs[t + 256] = gqk[b * 512 + t + 256];
  if (t < 16) scs[t] = sc[b * 16 + t];
  __syncthreads();  // the only block barrier

  float* xs = xs_all[w];
  float* pa = pa_all[w];

  const int g16 = lane >> 4;   // phase-2 row-in-group
  const int c16 = lane & 15;   // phase-2 col chunk

  float acc[7][4];
#pragma unroll
  for (int s = 0; s < 7; ++s)
#pragma unroll
    for (int i = 0; i < 4; ++i) acc[s][i] = 0.f;
  float zac[7] = {0, 0, 0, 0, 0, 0, 0};
  float zmc[7] = {0, 0, 0, 0, 0, 0, 0};

  float4 pf[16];
  // prologue: tile 0 -> regs -> LDS
  {
    const float4* src =
        reinterpret_cast<const float4*>(x + ((size_t)b * NN + rw0) * 64);
#pragma unroll
    for (int j = 0; j < 16; ++j) pf[j] = src[lane + 64 * j];
#pragma unroll
    for (int j = 0; j < 16; ++j) {
      const int f = lane + 64 * j;
      *reinterpret_cast<float4*>(&xs[(f >> 4) * XST + (f & 15) * 4]) = pf[j];
    }
  }

#pragma unroll
  for (int tI = 0; tI < TPW; ++tI) {
    // issue next tile's global loads early (latency hides under compute)
    if (tI + 1 < TPW) {
      const float4* src = reinterpret_cast<const float4*>(
          x + ((size_t)b * NN + rw0 + (tI + 1) * TROWS) * 64);
#pragma unroll
      for (int j = 0; j < 16; ++j) pf[j] = src[lane + 64 * j];
    }

    // ---- phase 1: thread-per-row (row = lane) ----
    {
      const float* xrow = xs + lane * XST;
      float lg[7] = {0, 0, 0, 0, 0, 0, 0};
      float sum = 0.f, sq = 0.f;
#pragma unroll
      for (int c = 0; c < 16; ++c) {
        const float4 v = *reinterpret_cast<const float4*>(&xrow[c * 4]);
        sum += v.x + v.y + v.z + v.w;
        sq = fmaf(v.x, v.x, fmaf(v.y, v.y, fmaf(v.z, v.z, fmaf(v.w, v.w, sq))));
#pragma unroll
        for (int s = 0; s < 7; ++s) {
          const float4 g =
              *reinterpret_cast<const float4*>(&qbs[s * 64 + c * 4]);
          lg[s] = fmaf(v.x, g.x,
                       fmaf(v.y, g.y, fmaf(v.z, g.z, fmaf(v.w, g.w, lg[s]))));
        }
      }
      const float mean = sum * (1.f / 64.f);
      const float var = sq * (1.f / 64.f) - mean * mean;
      const float rstd = rsqrtf(var + 1e-5f);
      const float rm = rstd * mean;
      float mx = -1e30f;
#pragma unroll
      for (int s = 0; s < 7; ++s) {
        lg[s] = rstd * lg[s] - rm * scs[s * 2] + scs[s * 2 + 1];
        mx = fmaxf(mx, lg[s]);
      }
      float se = 0.f;
#pragma unroll
      for (int s = 0; s < 7; ++s) {
        lg[s] = __expf(lg[s] - mx);
        se += lg[s];
      }
      const float inv = 1.f / se;
      float pr[7];
#pragma unroll
      for (int s = 0; s < 7; ++s) {
        const float p = lg[s] * inv + 1e-8f;
        pr[s] = p * rstd;
        zac[s] += p;
        zmc[s] = fmaf(p, rm, zmc[s]);
      }
      const float4 w1 = {pr[0], pr[1], pr[2], pr[3]};
      const float4 w2 = {pr[4], pr[5], pr[6], 0.f};
      *reinterpret_cast<float4*>(&pa[lane * 8]) = w1;
      *reinterpret_cast<float4*>(&pa[lane * 8 + 4]) = w2;
    }

    // ---- phase 2: rank-7 outer-product partials into registers ----
    // lane covers row n = n0+g16, cols 4*c16..+3; b128 reads, bank-even.
#pragma unroll 4
    for (int n0 = 0; n0 < TROWS; n0 += 4) {
      const int n = n0 + g16;
      const float4 xv =
          *reinterpret_cast<const float4*>(&xs[n * XST + c16 * 4]);
      const float4 p1 = *reinterpret_cast<const float4*>(&pa[n * 8]);
      const float4 p2 = *reinterpret_cast<const float4*>(&pa[n * 8 + 4]);
      const float ps[7] = {p1.x, p1.y, p1.z, p1.w, p2.x, p2.y, p2.z};
#pragma unroll
      for (int s = 0; s < 7; ++s) {
        acc[s][0] = fmaf(ps[s], xv.x, acc[s][0]);
        acc[s][1] = fmaf(ps[s], xv.y, acc[s][1]);
        acc[s][2] = fmaf(ps[s], xv.z, acc[s][2]);
        acc[s][3] = fmaf(ps[s], xv.w, acc[s][3]);
      }
    }

    // ---- write prefetched tile into LDS (after all reads of tile tI) ----
    if (tI + 1 < TPW) {
#pragma unroll
      for (int j = 0; j < 16; ++j) {
        const int f = lane + 64 * j;
        *reinterpret_cast<float4*>(&xs[(f >> 4) * XST + (f & 15) * 4]) = pf[j];
      }
    }
  }

  // ---- flush: reduce acc across the 4 row-groups, then atomics ----
#pragma unroll
  for (int s = 0; s < 7; ++s)
#pragma unroll
    for (int i = 0; i < 4; ++i) {
      acc[s][i] += __shfl_xor(acc[s][i], 16);
      acc[s][i] += __shfl_xor(acc[s][i], 32);
    }
  if (lane < 16) {
#pragma unroll
    for (int s = 0; s < 7; ++s)
#pragma unroll
      for (int i = 0; i < 4; ++i)
        atomicAdd(&ACC[(b * 8 + s) * 64 + lane * 4 + i], acc[s][i]);
  }
#pragma unroll
  for (int s = 0; s < 7; ++s) {
    const float z = wsum64(zac[s]);
    const float zm = wsum64(zmc[s]);
    if (lane == 0) {
      atomicAdd(&Zg[b * 8 + s], z);
      atomicAdd(&ACCM[b * 8 + s], zm);
    }
  }
}

extern "C" void kernel_launch(void* const* d_in, const int* in_sizes, int n_in,
                              void* d_out, int out_size, void* d_ws,
                              size_t ws_size, hipStream_t stream) {
  const float* inputs     = (const float*)d_in[0];
  const float* slots_init = (const float*)d_in[1];
  const float* slots_mu   = (const float*)d_in[2];
  const float* slots_lsig = (const float*)d_in[3];
  const float* ln_in_g    = (const float*)d_in[4];
  const float* ln_in_b    = (const float*)d_in[5];
  const float* ln_slot_g  = (const float*)d_in[6];
  const float* ln_slot_b  = (const float*)d_in[7];
  const float* ln_mlp_g   = (const float*)d_in[8];
  const float* ln_mlp_b   = (const float*)d_in[9];
  const float* Wq   = (const float*)d_in[10];
  const float* Wk   = (const float*)d_in[11];
  const float* Wv   = (const float*)d_in[12];
  const float* W_ih = (const float*)d_in[13];
  const float* W_hh = (const float*)d_in[14];
  const float* b_ih = (const float*)d_in[15];
  const float* b_hh = (const float*)d_in[16];
  const float* W1   = (const float*)d_in[17];
  const float* b1   = (const float*)d_in[18];
  const float* W2   = (const float*)d_in[19];
  const float* b2   = (const float*)d_in[20];

  float* ws    = (float*)d_ws;
  float* slots = ws;            // B*S*64 = 7168
  float* gqk   = ws + 7168;     // B*8*64 = 8192
  float* sc    = gqk + 8192;    // B*8*2  = 256
  float* ACC   = sc + 256;      // B*8*64 = 8192
  float* ACCM  = ACC + 8192;    // B*8    = 128
  float* Zg    = ACCM + 128;    // B*8    = 128

  float* out = (float*)d_out;

#define SLOT_ARGS                                                          \
  slots_init, slots_mu, slots_lsig, ln_slot_g, ln_slot_b, ln_mlp_g,        \
      ln_mlp_b, ln_in_g, ln_in_b, Wq, Wk, Wv, W_ih, W_hh, b_ih, b_hh, W1,  \
      b1, W2, b2, slots, gqk, sc, ACC, ACCM, Zg, out

  k_slot<<<112, 64, 0, stream>>>(0, SLOT_ARGS);
  for (int it = 0; it < 3; ++it) {
    k_main<<<NBLOCKS, 256, 0, stream>>>(inputs, gqk, sc, ACC, ACCM, Zg);
    k_slot<<<112, 64, 0, stream>>>(it == 2 ? 2 : 1, SLOT_ARGS);
  }
#undef SLOT_ARGS
}